// Round 17
// baseline (231.245 us; speedup 1.0000x reference)
//
#include <hip/hip_runtime.h>

// GeodesicShooting on [160^3,3] f32.
// Blur: three transpose-fused passes, each along the CONTIGUOUS axis (the only
// pattern measured at BW floor; strided-tap variants all plateaued 34-50 us):
//   P1: [z][y][x] --blur x--> [z][x][y]
//   P2: [z][x][y] --blur y--> [y][x][z]
//   P3: [y][x][z] --blur z, *2^-6--> [z][y][x]
// One template kernel: 32x32 tile per block, rows contiguous in blur axis with
// +-4 halo; global_load_lds staging; 32x32 LDS transpose; coalesced writes.
// Steps: R4 MLP gather + XCD swizzle (~24.5 us each, at traffic floor).
// Identity grid folded analytically: s = idx + 79.5*v.
// Parity: P1 vel->OUT ; P2 OUT->WS ; P3 WS->OUT ; steps OUT->WS->...->OUT.

constexpr int W = 160, H = 160, D = 160;
constexpr int NVOX = W * H * D;            // 4,096,000
constexpr int NSTEPS = 6;
constexpr float HSC = 79.5f;               // 0.5*(W-1)

typedef const __attribute__((address_space(1))) void* gas_t;
typedef __attribute__((address_space(3))) void* las_t;

__device__ __forceinline__ int iclamp(int v, int lo, int hi) {
    return v < lo ? lo : (v > hi ? hi : v);
}

// ---- transpose-blur pass ----
// read  cell (row r, window cell m): float addr = s*RS + (tB*32+r)*RR + (tC*32-4+m)*3
// write cell (row r, output o):      float addr = s*WS + (tC*32+o)*WO + (tB*32+r)*3
// Blur axis = window/m axis (contiguous, 40 cells incl. +-4 halo), masked at edges.
template<int RS, int RR, int WS, int WO>
__global__ void blur_t(const float* __restrict__ in, float* __restrict__ out,
                       const float* __restrict__ gk, float scale)
{
    __shared__ float4 raw4[1024];              // [32 rows][30 float4] linear (+pad)
    __shared__ __align__(16) float bt[32 * 100]; // transposed tile [o][r*3+c]

    int b = blockIdx.x;
    int bs = (b & 7) * 500 + (b >> 3);         // 4000 blocks, bijective XCD swizzle
    int s   = bs / 25;                         // slice 0..159
    int rem = bs % 25;
    int tB  = rem / 5;                         // row-tile 0..4
    int tC  = rem % 5;                         // blur-axis tile 0..4
    int tid = threadIdx.x;

    float kw[9];
#pragma unroll
    for (int t = 0; t < 9; ++t) kw[t] = gk[t] * scale;

    // ---- stage: 32 rows x 120 floats (40 cells) as 960 float4, lane-linear ----
#pragma unroll
    for (int k = 0; k < 4; ++k) {
        int j4 = k * 256 + tid;
        int jc = j4 < 960 ? j4 : 959;          // pad slots load a safe addr
        int row = jc / 30, c4 = jc % 30;
        int foff = (tC * 32 - 4) * 3 + 4 * c4; // window float offset in the row
        foff = iclamp(foff, 0, 476);           // clamped; garbage lands in masked cells
        const float* src = in + (size_t)s * RS + (size_t)(tB * 32 + row) * RR + foff;
        __builtin_amdgcn_global_load_lds((gas_t)src, (las_t)&raw4[j4], 16, 0, 0);
    }
    __syncthreads();

    // ---- blur along window axis: one 4-output group per thread ----
    {
        int r  = tid / 8;                      // row 0..31
        int o0 = (tid % 8) * 4;                // first output cell 0,4,..28
        float4 wf[9];
        int base4 = r * 30 + (o0 * 3) / 4;     // window floats o0*3 .. o0*3+35
#pragma unroll
        for (int k = 0; k < 9; ++k) wf[k] = raw4[base4 + k];
        const float* wv = (const float*)wf;    // 36 floats = cells o0..o0+11

#pragma unroll
        for (int j = 0; j < 4; ++j) {          // output cell o = o0+j
            int o = o0 + j;
            float a0 = 0.f, a1 = 0.f, a2 = 0.f;
#pragma unroll
            for (int k = 0; k < 9; ++k) {
                // axis coord of tap = tC*32 + o + k - 4 ; zero-pad via weight
                float w = ((unsigned)(tC * 32 + o + k - 4) < 160u) ? kw[k] : 0.0f;
                a0 = fmaf(w, wv[(j + k) * 3 + 0], a0);
                a1 = fmaf(w, wv[(j + k) * 3 + 1], a1);
                a2 = fmaf(w, wv[(j + k) * 3 + 2], a2);
            }
            bt[o * 100 + r * 3 + 0] = a0;      // transposed store [o][r]
            bt[o * 100 + r * 3 + 1] = a1;
            bt[o * 100 + r * 3 + 2] = a2;
        }
    }
    __syncthreads();

    // ---- write: 768 float4, rows contiguous in r (new innermost axis) ----
#pragma unroll
    for (int k = 0; k < 3; ++k) {
        int j4 = k * 256 + tid;
        int o  = j4 / 24;                      // output cell along blur axis
        int c4 = j4 % 24;                      // float4 within the 96-float row
        float4 v = *(const float4*)&bt[o * 100 + c4 * 4];
        float* dst = out + (size_t)s * WS + (size_t)(tC * 32 + o) * WO
                   + (size_t)tB * 96 + (size_t)c4 * 4;
        *(float4*)dst = v;
    }
}

// ---- one scaling-and-squaring step: out = v + trilerp(v, id + v), AoS ----
__global__ void step_kernel(const float* __restrict__ v, float* __restrict__ out)
{
    int b = blockIdx.x;
    int bs = (b & 7) * 2000 + (b >> 3);                 // bijective XCD swizzle
    int i = bs * blockDim.x + threadIdx.x;
    int x = i % W;
    int t = i / W;
    int y = t % H;
    int z = t / H;

    const float* pv = v + (size_t)i * 3;
    float vx = pv[0], vy = pv[1], vz = pv[2];

    float sx = fmaf(vx, HSC, (float)x);
    float sy = fmaf(vy, HSC, (float)y);
    float sz = fmaf(vz, HSC, (float)z);

    float fx = floorf(sx), fy = floorf(sy), fz = floorf(sz);
    int x0 = (int)fx, y0 = (int)fy, z0 = (int)fz;
    float wx1 = sx - fx, wy1 = sy - fy, wz1 = sz - fz;
    float wx0 = 1.f - wx1, wy0 = 1.f - wy1, wz0 = 1.f - wz1;

    wx0 *= (x0     >= 0 && x0     < W) ? 1.f : 0.f;
    wx1 *= (x0 + 1 >= 0 && x0 + 1 < W) ? 1.f : 0.f;
    wy0 *= (y0     >= 0 && y0     < H) ? 1.f : 0.f;
    wy1 *= (y0 + 1 >= 0 && y0 + 1 < H) ? 1.f : 0.f;
    wz0 *= (z0     >= 0 && z0     < D) ? 1.f : 0.f;
    wz1 *= (z0 + 1 >= 0 && z0 + 1 < D) ? 1.f : 0.f;

    int xc0 = iclamp(x0, 0, W - 1), xc1 = iclamp(x0 + 1, 0, W - 1);
    int yc0 = iclamp(y0, 0, H - 1), yc1 = iclamp(y0 + 1, 0, H - 1);
    int zc0 = iclamp(z0, 0, D - 1), zc1 = iclamp(z0 + 1, 0, D - 1);

    int idx[8];
    idx[0] = (zc0 * H + yc0) * W + xc0;
    idx[1] = (zc0 * H + yc0) * W + xc1;
    idx[2] = (zc0 * H + yc1) * W + xc0;
    idx[3] = (zc0 * H + yc1) * W + xc1;
    idx[4] = (zc1 * H + yc0) * W + xc0;
    idx[5] = (zc1 * H + yc0) * W + xc1;
    idx[6] = (zc1 * H + yc1) * W + xc0;
    idx[7] = (zc1 * H + yc1) * W + xc1;

    float c[8][3];
#pragma unroll
    for (int k = 0; k < 8; ++k) {
        const float* p = v + (size_t)idx[k] * 3;
        c[k][0] = p[0];
        c[k][1] = p[1];
        c[k][2] = p[2];
    }

    float w8[8];
    w8[0] = wz0 * wy0 * wx0;
    w8[1] = wz0 * wy0 * wx1;
    w8[2] = wz0 * wy1 * wx0;
    w8[3] = wz0 * wy1 * wx1;
    w8[4] = wz1 * wy0 * wx0;
    w8[5] = wz1 * wy0 * wx1;
    w8[6] = wz1 * wy1 * wx0;
    w8[7] = wz1 * wy1 * wx1;

    float r0 = vx, r1 = vy, r2 = vz;
#pragma unroll
    for (int k = 0; k < 8; ++k) {
        r0 = fmaf(w8[k], c[k][0], r0);
        r1 = fmaf(w8[k], c[k][1], r1);
        r2 = fmaf(w8[k], c[k][2], r2);
    }

    float* q = out + (size_t)i * 3;
    q[0] = r0;
    q[1] = r1;
    q[2] = r2;
}

extern "C" void kernel_launch(void* const* d_in, const int* in_sizes, int n_in,
                              void* d_out, int out_size, void* d_ws, size_t ws_size,
                              hipStream_t stream)
{
    const float* vel = (const float*)d_in[0];
    // d_in[1] (identity grid) folded analytically
    const float* gk  = (const float*)d_in[2];   // 9 taps

    float* OUT = (float*)d_out;
    float* WS  = (float*)d_ws;                  // one [NVOX,3] f32 buffer

    const int threads = 256;
    const int tBlocks    = 160 * 5 * 5;                 // 4000 (% 8 == 0)
    const int stepBlocks = NVOX / threads;              // 16000
    const float scale = 1.0f / (float)(1 << NSTEPS);    // 2^-6

    // P1: [z][y][x] blur x -> [z][x][y]   (vel -> OUT)
    blur_t<76800, 480, 76800, 480><<<tBlocks, threads, 0, stream>>>(vel, OUT, gk, 1.0f);
    // P2: [z][x][y] blur y -> [y][x][z]   (OUT -> WS)
    blur_t<480, 76800, 480, 76800><<<tBlocks, threads, 0, stream>>>(OUT, WS, gk, 1.0f);
    // P3: [y][x][z] blur z -> [z][y][x], scale fused   (WS -> OUT)
    blur_t<76800, 480, 480, 76800><<<tBlocks, threads, 0, stream>>>(WS, OUT, gk, scale);

    // 6 squaring steps: OUT -> WS -> OUT -> WS -> OUT -> WS -> OUT
    step_kernel<<<stepBlocks, threads, 0, stream>>>(OUT, WS);
    step_kernel<<<stepBlocks, threads, 0, stream>>>(WS, OUT);
    step_kernel<<<stepBlocks, threads, 0, stream>>>(OUT, WS);
    step_kernel<<<stepBlocks, threads, 0, stream>>>(WS, OUT);
    step_kernel<<<stepBlocks, threads, 0, stream>>>(OUT, WS);
    step_kernel<<<stepBlocks, threads, 0, stream>>>(WS, OUT);
}

// Round 18
// 227.079 us; speedup vs baseline: 1.0183x; 1.0183x over previous
//
#include <hip/hip_runtime.h>

// GeodesicShooting on [160^3,3] f32, AoS layout. FINAL = R13 (best measured,
// 227.06 us): z-blur + fused yx-blur staged via __builtin_amdgcn_global_load_lds
// (no VGPR round-trip, single vmcnt drain), zero-padding via compute-time
// weight masks; steps = 8-corner batched-MLP gather + bijective XCD swizzle.
// Blur plateau 75-84 us confirmed across 9 structural variants (streaming, MLP
// batch, LDS tile, DMA, transpose-fused) -> practical multi-stream stencil BW
// ~3-3.5 TB/s. Steps ~24.5 us each, ~95% of gather-traffic floor.
// Identity grid folded analytically: s = idx + 79.5*v.
// Parity: z vel->WS ; yx WS->OUT(scale) ; steps OUT->WS->...->OUT (6 steps).

constexpr int W = 160, H = 160, D = 160;
constexpr int NVOX = W * H * D;            // 4,096,000
constexpr int NSTEPS = 6;
constexpr float HSC = 79.5f;               // 0.5*(W-1)

constexpr int ZT = 8;                      // z outputs per block
constexpr int ZR = ZT + 8;                 // 16 staged z-rows
constexpr int ZSTG = ZR * 120;             // 1920 staged float4
constexpr int ZPAD = 2048;                 // 8 * 256 slots

constexpr int YT = 8;                      // y outputs per block
constexpr int XT = 80;                     // x outputs per block (half row)
constexpr int YR = YT + 8;                 // 16 staged rows
constexpr int XRG = 22;                    // staged 4-voxel col groups (88 voxels)
constexpr int XOG = 20;                    // output 4-voxel col groups
constexpr int YXSTG = YR * XRG * 3;        // 1056 staged float4
constexpr int YXPAD = 1280;                // 5 * 256 slots

typedef const __attribute__((address_space(1))) void* gas_t;
typedef __attribute__((address_space(3))) void* las_t;

__device__ __forceinline__ int iclamp(int v, int lo, int hi) {
    return v < lo ? lo : (v > hi ? hi : v);
}

// ---- blur along z: global_load_lds staging, weight-masked zero padding ----
__global__ void blur_z_lds4(const float* __restrict__ in, float* __restrict__ out,
                            const float* __restrict__ gk)
{
    __shared__ float4 raw[ZPAD];           // 32 KB -> 5 blocks/CU

    int b = blockIdx.x;
    int bs = (b & 7) * 400 + (b >> 3);     // 3200 blocks, bijective XCD swizzle
    int y    = bs % H;
    int zseg = bs / H;                     // 0..19
    int z0 = zseg * ZT;
    int tid = threadIdx.x;

    float kw[9];
#pragma unroll
    for (int t = 0; t < 9; ++t) kw[t] = gk[t];

    // staging: 8 global_load_lds per thread, ALL in flight, one drain at barrier
#pragma unroll
    for (int k = 0; k < 8; ++k) {
        int j  = k * 256 + tid;
        int jc = j < ZSTG ? j : ZSTG - 1;           // pad slots load safe addr
        int row = jc / 120, col = jc % 120;
        int zz = iclamp(z0 - 4 + row, 0, D - 1);    // clamped; masked by weight
        const float* gsrc = in + ((size_t)zz * H + y) * 480 + (size_t)col * 4;
        __builtin_amdgcn_global_load_lds((gas_t)gsrc, (las_t)&raw[j], 16, 0, 0);
    }
    __syncthreads();

    // compute 8 z x 40 col-groups (4 voxels each); zero-pad via weight mask
    for (int j = tid; j < ZT * 40; j += 256) {
        int xg = j % 40;
        int t  = j / 40;
        float a[12] = {0,0,0,0,0,0,0,0,0,0,0,0};
#pragma unroll
        for (int k = 0; k < 9; ++k) {
            float w = ((unsigned)(z0 - 4 + t + k) < (unsigned)D) ? kw[k] : 0.0f;
            const float4* r = &raw[(t + k) * 120 + xg * 3];
            float4 u0 = r[0], u1 = r[1], u2 = r[2];
            a[0]  = fmaf(w, u0.x, a[0]);  a[1]  = fmaf(w, u0.y, a[1]);
            a[2]  = fmaf(w, u0.z, a[2]);  a[3]  = fmaf(w, u0.w, a[3]);
            a[4]  = fmaf(w, u1.x, a[4]);  a[5]  = fmaf(w, u1.y, a[5]);
            a[6]  = fmaf(w, u1.z, a[6]);  a[7]  = fmaf(w, u1.w, a[7]);
            a[8]  = fmaf(w, u2.x, a[8]);  a[9]  = fmaf(w, u2.y, a[9]);
            a[10] = fmaf(w, u2.z, a[10]); a[11] = fmaf(w, u2.w, a[11]);
        }
        float4* q = (float4*)(out + ((size_t)(z0 + t) * H + y) * 480 + (size_t)xg * 12);
        q[0] = make_float4(a[0], a[1], a[2],  a[3]);
        q[1] = make_float4(a[4], a[5], a[6],  a[7]);
        q[2] = make_float4(a[8], a[9], a[10], a[11]);
    }
}

// ---- fused y-blur + x-blur (+ 2^-6 scale), global_load_lds staging ----
__global__ void blur_yx_lds4(const float* __restrict__ in, float* __restrict__ out,
                             const float* __restrict__ gk, float scale)
{
    __shared__ float4 raw[YXPAD];          // 20.5 KB
    __shared__ float4 yb [YT * XRG * 3];   //  8.4 KB -> ~29 KB, 5 blocks/CU

    int b = blockIdx.x;
    int bs = (b & 7) * 800 + (b >> 3);     // 6400 blocks, bijective
    int xh   = bs % 2;
    int t2   = bs / 2;
    int yseg = t2 % 20;
    int z    = t2 / 20;
    int y0 = yseg * YT;
    int x0 = xh * XT;
    int tid = threadIdx.x;

    float kw[9];
#pragma unroll
    for (int t = 0; t < 9; ++t) kw[t] = gk[t];

    const size_t planeBase = (size_t)z * H * W * 3;    // floats

    // staging: 5 global_load_lds per thread (clamped addresses, no select)
#pragma unroll
    for (int k = 0; k < 5; ++k) {
        int j  = k * 256 + tid;
        int jc = j < YXSTG ? j : YXSTG - 1;
        int row = jc / (XRG * 3);
        int rem = jc % (XRG * 3);
        int g = rem / 3, u = rem % 3;
        int yy = iclamp(y0 - 4 + row, 0, H - 1);
        int xb = iclamp(x0 - 4 + g * 4, 0, W - 4);
        const float* gsrc = in + planeBase + ((size_t)yy * W + xb) * 3 + (size_t)u * 4;
        __builtin_amdgcn_global_load_lds((gas_t)gsrc, (las_t)&raw[j], 16, 0, 0);
    }
    __syncthreads();

    // y-blur: 8 rows x 22 groups; y zero-pad via weight mask
    for (int j = tid; j < YT * XRG; j += 256) {
        int g   = j % XRG;
        int row = j / XRG;
        float a[12] = {0,0,0,0,0,0,0,0,0,0,0,0};
#pragma unroll
        for (int k = 0; k < 9; ++k) {
            float w = ((unsigned)(y0 - 4 + row + k) < (unsigned)H) ? kw[k] : 0.0f;
            const float4* r = &raw[(row + k) * (XRG * 3) + g * 3];
            float4 u0 = r[0], u1 = r[1], u2 = r[2];
            a[0]  = fmaf(w, u0.x, a[0]);  a[1]  = fmaf(w, u0.y, a[1]);
            a[2]  = fmaf(w, u0.z, a[2]);  a[3]  = fmaf(w, u0.w, a[3]);
            a[4]  = fmaf(w, u1.x, a[4]);  a[5]  = fmaf(w, u1.y, a[5]);
            a[6]  = fmaf(w, u1.z, a[6]);  a[7]  = fmaf(w, u1.w, a[7]);
            a[8]  = fmaf(w, u2.x, a[8]);  a[9]  = fmaf(w, u2.y, a[9]);
            a[10] = fmaf(w, u2.z, a[10]); a[11] = fmaf(w, u2.w, a[11]);
        }
        yb[row * (XRG * 3) + g * 3 + 0] = make_float4(a[0], a[1], a[2],  a[3]);
        yb[row * (XRG * 3) + g * 3 + 1] = make_float4(a[4], a[5], a[6],  a[7]);
        yb[row * (XRG * 3) + g * 3 + 2] = make_float4(a[8], a[9], a[10], a[11]);
    }
    __syncthreads();

    // x-blur + scale: 8 rows x 20 groups; x zero-pad via weight mask
    for (int j = tid; j < YT * XOG; j += 256) {
        int xg = j % XOG;
        int yo = j / XOG;
        float wv[36];
#pragma unroll
        for (int m = 0; m < 9; ++m) {
            float4 u = yb[yo * (XRG * 3) + xg * 3 + m];
            wv[4 * m + 0] = u.x; wv[4 * m + 1] = u.y;
            wv[4 * m + 2] = u.z; wv[4 * m + 3] = u.w;
        }
        float o[12];
#pragma unroll
        for (int jj = 0; jj < 4; ++jj) {
#pragma unroll
            for (int cth = 0; cth < 3; ++cth) {
                float s = 0.f;
#pragma unroll
                for (int t = 0; t < 9; ++t) {
                    // staged voxel xg*4+jj+t  <->  global x = x0-4+xg*4+jj+t
                    float w = ((unsigned)(x0 - 4 + xg * 4 + jj + t) < (unsigned)W)
                                  ? kw[t] : 0.0f;
                    s = fmaf(w, wv[3 * (jj + t) + cth], s);
                }
                o[3 * jj + cth] = s * scale;
            }
        }
        float4* q = (float4*)(out + planeBase +
            ((size_t)(y0 + yo) * W + (x0 + xg * 4)) * 3);
        q[0] = make_float4(o[0], o[1], o[2],  o[3]);
        q[1] = make_float4(o[4], o[5], o[6],  o[7]);
        q[2] = make_float4(o[8], o[9], o[10], o[11]);
    }
}

// ---- one scaling-and-squaring step: out = v + trilerp(v, id + v), AoS ----
__global__ void step_kernel(const float* __restrict__ v, float* __restrict__ out)
{
    int b = blockIdx.x;
    int bs = (b & 7) * 2000 + (b >> 3);                 // bijective XCD swizzle
    int i = bs * blockDim.x + threadIdx.x;
    int x = i % W;
    int t = i / W;
    int y = t % H;
    int z = t / H;

    const float* pv = v + (size_t)i * 3;
    float vx = pv[0], vy = pv[1], vz = pv[2];

    float sx = fmaf(vx, HSC, (float)x);
    float sy = fmaf(vy, HSC, (float)y);
    float sz = fmaf(vz, HSC, (float)z);

    float fx = floorf(sx), fy = floorf(sy), fz = floorf(sz);
    int x0 = (int)fx, y0 = (int)fy, z0 = (int)fz;
    float wx1 = sx - fx, wy1 = sy - fy, wz1 = sz - fz;
    float wx0 = 1.f - wx1, wy0 = 1.f - wy1, wz0 = 1.f - wz1;

    wx0 *= (x0     >= 0 && x0     < W) ? 1.f : 0.f;
    wx1 *= (x0 + 1 >= 0 && x0 + 1 < W) ? 1.f : 0.f;
    wy0 *= (y0     >= 0 && y0     < H) ? 1.f : 0.f;
    wy1 *= (y0 + 1 >= 0 && y0 + 1 < H) ? 1.f : 0.f;
    wz0 *= (z0     >= 0 && z0     < D) ? 1.f : 0.f;
    wz1 *= (z0 + 1 >= 0 && z0 + 1 < D) ? 1.f : 0.f;

    int xc0 = iclamp(x0, 0, W - 1), xc1 = iclamp(x0 + 1, 0, W - 1);
    int yc0 = iclamp(y0, 0, H - 1), yc1 = iclamp(y0 + 1, 0, H - 1);
    int zc0 = iclamp(z0, 0, D - 1), zc1 = iclamp(z0 + 1, 0, D - 1);

    int idx[8];
    idx[0] = (zc0 * H + yc0) * W + xc0;
    idx[1] = (zc0 * H + yc0) * W + xc1;
    idx[2] = (zc0 * H + yc1) * W + xc0;
    idx[3] = (zc0 * H + yc1) * W + xc1;
    idx[4] = (zc1 * H + yc0) * W + xc0;
    idx[5] = (zc1 * H + yc0) * W + xc1;
    idx[6] = (zc1 * H + yc1) * W + xc0;
    idx[7] = (zc1 * H + yc1) * W + xc1;

    float c[8][3];
#pragma unroll
    for (int k = 0; k < 8; ++k) {
        const float* p = v + (size_t)idx[k] * 3;
        c[k][0] = p[0];
        c[k][1] = p[1];
        c[k][2] = p[2];
    }

    float w8[8];
    w8[0] = wz0 * wy0 * wx0;
    w8[1] = wz0 * wy0 * wx1;
    w8[2] = wz0 * wy1 * wx0;
    w8[3] = wz0 * wy1 * wx1;
    w8[4] = wz1 * wy0 * wx0;
    w8[5] = wz1 * wy0 * wx1;
    w8[6] = wz1 * wy1 * wx0;
    w8[7] = wz1 * wy1 * wx1;

    float r0 = vx, r1 = vy, r2 = vz;
#pragma unroll
    for (int k = 0; k < 8; ++k) {
        r0 = fmaf(w8[k], c[k][0], r0);
        r1 = fmaf(w8[k], c[k][1], r1);
        r2 = fmaf(w8[k], c[k][2], r2);
    }

    float* q = out + (size_t)i * 3;
    q[0] = r0;
    q[1] = r1;
    q[2] = r2;
}

extern "C" void kernel_launch(void* const* d_in, const int* in_sizes, int n_in,
                              void* d_out, int out_size, void* d_ws, size_t ws_size,
                              hipStream_t stream)
{
    const float* vel = (const float*)d_in[0];
    // d_in[1] (identity grid) folded analytically
    const float* gk  = (const float*)d_in[2];   // 9 taps

    float* OUT = (float*)d_out;
    float* WS  = (float*)d_ws;                  // one [NVOX,3] f32 buffer

    const int threads = 256;
    const int zBlocks   = H * (D / ZT);                     // 3200
    const int yxBlocks  = D * (H / YT) * (W / XT);          // 6400
    const int stepBlocks = NVOX / threads;                  // 16000
    const float scale = 1.0f / (float)(1 << NSTEPS);        // 2^-6

    // blur: vel -> WS (z), WS -> OUT (y+x fused, scaled)
    blur_z_lds4 <<<zBlocks,  threads, 0, stream>>>(vel, WS, gk);
    blur_yx_lds4<<<yxBlocks, threads, 0, stream>>>(WS, OUT, gk, scale);

    // 6 squaring steps: OUT -> WS -> OUT -> WS -> OUT -> WS -> OUT
    step_kernel<<<stepBlocks, threads, 0, stream>>>(OUT, WS);
    step_kernel<<<stepBlocks, threads, 0, stream>>>(WS, OUT);
    step_kernel<<<stepBlocks, threads, 0, stream>>>(OUT, WS);
    step_kernel<<<stepBlocks, threads, 0, stream>>>(WS, OUT);
    step_kernel<<<stepBlocks, threads, 0, stream>>>(OUT, WS);
    step_kernel<<<stepBlocks, threads, 0, stream>>>(WS, OUT);
}